// Round 1
// baseline (661.789 us; speedup 1.0000x reference)
//
#include <hip/hip_runtime.h>
#include <float.h>

// FocalLossAdaptive: per-row log_softmax at target, adaptive gamma, summed.
// N=4096 rows, C=32000 cols fp32. Memory-bound: 524 MB single HBM read.
//
// R4 theory: previous variants loaded two float4 per thread at 32-B lane
// stride (each dwordx4 spanning 2 KB with half-line utilization, relying on
// cross-instruction line merging). Suspected cause of the ~1.6 TB/s plateau
// (4x off achievable). This version uses textbook-dense loads: one float4
// per lane per instruction (16-B lane stride, contiguous 1 KB per wave-load,
// contiguous 4 KB per unroll group), NSTR=4 independent online-softmax
// streams for MLP. 7 full trips per row + short block-stride tail.
// Stage 2: one block reduces ws[0..N) -> out[0].

#define BLOCK 256
#define NSTR 4

__device__ __forceinline__ void merge_chunk(float& m, float& s, float c, float e) {
  // branchless merge of chunk (c, e) into running (m, s); exactly one exp.
  float M = fmaxf(m, c);
  float d = __expf(fminf(m, c) - M);   // m = -FLT_MAX: d = 0, s = e
  s = (c > m) ? fmaf(s, d, e) : fmaf(e, d, s);
  m = M;
}

__global__ __launch_bounds__(BLOCK) void focal_row_kernel(
    const float* __restrict__ input,
    const int* __restrict__ target,
    float* __restrict__ row_loss,
    int C) {
  const int row = blockIdx.x;
  const int tid = threadIdx.x;
  const float* __restrict__ rowp = input + (size_t)row * (size_t)C;
  const float4* __restrict__ row4 = reinterpret_cast<const float4*>(rowp);

  float m[NSTR], s[NSTR];
#pragma unroll
  for (int j = 0; j < NSTR; ++j) { m[j] = -FLT_MAX; s[j] = 0.0f; }

  const int nvec = C >> 2;  // float4 count per row (8000 for C=32000)
  int k = tid;
  // Main loop: NSTR independent dense float4 loads per trip.
  // Lane stride within each load = 16 B (fully coalesced); streams are
  // 1 KB apart so the 4 loads cover a contiguous 4 KB per wave per trip.
  for (; k + (NSTR - 1) * BLOCK < nvec; k += NSTR * BLOCK) {
    float4 v[NSTR];
#pragma unroll
    for (int j = 0; j < NSTR; ++j) v[j] = row4[k + j * BLOCK];
#pragma unroll
    for (int j = 0; j < NSTR; ++j) {
      float c = fmaxf(fmaxf(v[j].x, v[j].y), fmaxf(v[j].z, v[j].w));
      float e = __expf(v[j].x - c) + __expf(v[j].y - c) +
                __expf(v[j].z - c) + __expf(v[j].w - c);
      merge_chunk(m[j], s[j], c, e);
    }
  }
  // Remainder float4s -> stream 0 (832 float4 for C=32000: ~3.25/thread).
  for (; k < nvec; k += BLOCK) {
    float4 v = row4[k];
    float c = fmaxf(fmaxf(v.x, v.y), fmaxf(v.z, v.w));
    float e = __expf(v.x - c) + __expf(v.y - c) +
              __expf(v.z - c) + __expf(v.w - c);
    merge_chunk(m[0], s[0], c, e);
  }
  // Scalar tail elements (C % 4; none for C=32000 but keep generic).
  for (int i = (nvec << 2) + tid; i < C; i += BLOCK) {
    merge_chunk(m[0], s[0], rowp[i], 1.0f);
  }

  // Merge the NSTR streams.
#pragma unroll
  for (int j = 1; j < NSTR; ++j) {
    float M = fmaxf(m[0], m[j]);
    float d = __expf(fminf(m[0], m[j]) - M);
    s[0] = (m[j] > m[0]) ? fmaf(s[0], d, s[j]) : fmaf(s[j], d, s[0]);
    m[0] = M;
  }
  float mm = m[0], ss = s[0];

  // Wave-level (64-lane) pairwise merge of (mm, ss).
#pragma unroll
  for (int off = 32; off > 0; off >>= 1) {
    float mo = __shfl_down(mm, off);
    float so = __shfl_down(ss, off);
    float M = fmaxf(mm, mo);
    ss = ss * __expf(mm - M) + so * __expf(mo - M);
    mm = M;
  }

  __shared__ float sm[BLOCK / 64];
  __shared__ float sw[BLOCK / 64];
  const int wave = tid >> 6;
  const int lane = tid & 63;
  if (lane == 0) { sm[wave] = mm; sw[wave] = ss; }
  __syncthreads();

  if (tid == 0) {
    const int nw = BLOCK / 64;
    float M = sm[0];
#pragma unroll
    for (int w = 1; w < nw; ++w) M = fmaxf(M, sm[w]);
    float S = 0.0f;
#pragma unroll
    for (int w = 0; w < nw; ++w) S += sw[w] * __expf(sm[w] - M);

    const int t = target[row];
    const float xt = rowp[t];          // single 4-B re-read
    const float logpt = xt - M - __logf(S);
    const float pt = __expf(logpt);
    const float om = 1.0f - pt;
    const float w3 = om * om * om;
    // gamma: pt >= 0.5 -> 3; pt < 0.2 -> 5; else -> 3  ==> (pt<0.2) ? 5 : 3
    const float wgt = (pt < 0.2f) ? w3 * om * om : w3;
    row_loss[row] = -wgt * logpt;      // plain store; no atomic contention
  }
}

__global__ __launch_bounds__(BLOCK) void reduce_kernel(
    const float* __restrict__ row_loss, float* __restrict__ out, int N) {
  const int tid = threadIdx.x;
  float s = 0.0f;
  for (int i = tid; i < N; i += BLOCK) s += row_loss[i];
#pragma unroll
  for (int off = 32; off > 0; off >>= 1) s += __shfl_down(s, off);
  __shared__ float sw[BLOCK / 64];
  if ((tid & 63) == 0) sw[tid >> 6] = s;
  __syncthreads();
  if (tid == 0) out[0] = sw[0] + sw[1] + sw[2] + sw[3];
}

extern "C" void kernel_launch(void* const* d_in, const int* in_sizes, int n_in,
                              void* d_out, int out_size, void* d_ws, size_t ws_size,
                              hipStream_t stream) {
  const float* input = (const float*)d_in[0];
  const int* target = (const int*)d_in[1];
  float* out = (float*)d_out;
  float* row_loss = (float*)d_ws;      // N floats of scratch

  const int N = in_sizes[1];            // 4096 rows
  const int C = in_sizes[0] / N;        // 32000 cols

  focal_row_kernel<<<dim3(N), dim3(BLOCK), 0, stream>>>(input, target, row_loss, C);
  reduce_kernel<<<dim3(1), dim3(BLOCK), 0, stream>>>(row_loss, out, N);
}

// Round 2
// 661.037 us; speedup vs baseline: 1.0011x; 1.0011x over previous
//
#include <hip/hip_runtime.h>
#include <float.h>

// FocalLossAdaptive: per-row log_softmax at target, adaptive gamma, summed.
// N=4096 rows, C=32000 cols fp32. Memory-bound: 524 MB single HBM read.
//
// R5 theory: three different load patterns (32B-stride pairs, dense NSTR=4)
// all measured ~1.6 TB/s (~320-330 us) -- 4x off the 6.4 TB/s this run's
// poison fill achieves. Latency arithmetic says the one-block-per-row
// decomposition (4096 blocks, 128 KB/row, 16 sequential rounds/CU) should
// still saturate, so this round probes the only un-probed axis: work
// decomposition. SPLIT=4 segments per row -> 16384 blocks (64/CU), each
// streaming a dense 32-KB segment with NSTR=4 independent online-softmax
// streams; per-segment (m,s) partials + cache-hot capture of the target
// logit go to workspace; a single-block finalize kernel merges partials,
// applies the focal weight, and sums.
// Predicted: partial kernel ~90-120 us @ 4.5-6 TB/s => dur_us ~430-460.
// If dur_us stays ~661, decomposition is falsified -> probe the read path.

#define BLOCK 256
#define NSTR 4
#define SPLIT 4
#define BLK2 1024

__device__ __forceinline__ void merge_chunk(float& m, float& s, float c, float e) {
  // branchless merge of chunk (c, e) into running (m, s); exactly one exp.
  float M = fmaxf(m, c);
  float d = __expf(fminf(m, c) - M);   // m = -FLT_MAX: d = 0, s = e
  s = (c > m) ? fmaf(s, d, e) : fmaf(e, d, s);
  m = M;
}

__global__ __launch_bounds__(BLOCK) void partial_softmax_kernel(
    const float* __restrict__ input,
    const int* __restrict__ target,
    float2* __restrict__ partial,     // [SPLIT][N] (m_seg, s_seg)
    float* __restrict__ xt_out,       // [N] target logit, captured cache-hot
    int C) {
  const int bid = blockIdx.x;
  const int row = bid / SPLIT;
  const int seg = bid % SPLIT;
  const int N = gridDim.x / SPLIT;
  const int tid = threadIdx.x;
  const float* __restrict__ rowp = input + (size_t)row * (size_t)C;
  const float4* __restrict__ row4 = reinterpret_cast<const float4*>(rowp);

  const int nvec = C >> 2;                        // float4 count per row
  const int segLen = nvec / SPLIT;
  const int base = seg * segLen;
  const int end = (seg == SPLIT - 1) ? nvec : base + segLen;

  // Capture the target logit if it falls in this segment (exactly one seg
  // per row matches; the line is about to be streamed anyway -> cheap).
  if (tid == 0) {
    const int t = target[row];
    const int fbeg = base << 2;
    const int fend = (seg == SPLIT - 1) ? C : (end << 2);
    if (t >= fbeg && t < fend) xt_out[row] = rowp[t];
  }

  float m[NSTR], s[NSTR];
#pragma unroll
  for (int j = 0; j < NSTR; ++j) { m[j] = -FLT_MAX; s[j] = 0.0f; }

  int k = base + tid;
  // Main loop: NSTR independent dense float4 loads per trip (16-B lane
  // stride; the 4 loads cover a contiguous 16 KB per block per trip).
  for (; k + (NSTR - 1) * BLOCK < end; k += NSTR * BLOCK) {
    float4 v[NSTR];
#pragma unroll
    for (int j = 0; j < NSTR; ++j) v[j] = row4[k + j * BLOCK];
#pragma unroll
    for (int j = 0; j < NSTR; ++j) {
      float c = fmaxf(fmaxf(v[j].x, v[j].y), fmaxf(v[j].z, v[j].w));
      float e = __expf(v[j].x - c) + __expf(v[j].y - c) +
                __expf(v[j].z - c) + __expf(v[j].w - c);
      merge_chunk(m[j], s[j], c, e);
    }
  }
  // Remainder float4s -> stream 0.
  for (; k < end; k += BLOCK) {
    float4 v = row4[k];
    float c = fmaxf(fmaxf(v.x, v.y), fmaxf(v.z, v.w));
    float e = __expf(v.x - c) + __expf(v.y - c) +
              __expf(v.z - c) + __expf(v.w - c);
    merge_chunk(m[0], s[0], c, e);
  }
  // Scalar tail elements (C % 4; only the last segment owns them).
  if (seg == SPLIT - 1) {
    for (int i = (nvec << 2) + tid; i < C; i += BLOCK) {
      merge_chunk(m[0], s[0], rowp[i], 1.0f);
    }
  }

  // Merge the NSTR streams.
#pragma unroll
  for (int j = 1; j < NSTR; ++j) {
    float M = fmaxf(m[0], m[j]);
    float d = __expf(fminf(m[0], m[j]) - M);
    s[0] = (m[j] > m[0]) ? fmaf(s[0], d, s[j]) : fmaf(s[j], d, s[0]);
    m[0] = M;
  }
  float mm = m[0], ss = s[0];

  // Wave-level (64-lane) pairwise merge of (mm, ss).
#pragma unroll
  for (int off = 32; off > 0; off >>= 1) {
    float mo = __shfl_down(mm, off);
    float so = __shfl_down(ss, off);
    float M = fmaxf(mm, mo);
    ss = ss * __expf(mm - M) + so * __expf(mo - M);
    mm = M;
  }

  __shared__ float sm[BLOCK / 64];
  __shared__ float sw[BLOCK / 64];
  const int wave = tid >> 6;
  const int lane = tid & 63;
  if (lane == 0) { sm[wave] = mm; sw[wave] = ss; }
  __syncthreads();

  if (tid == 0) {
    const int nw = BLOCK / 64;
    float M = sm[0];
#pragma unroll
    for (int w = 1; w < nw; ++w) M = fmaxf(M, sm[w]);
    float S = 0.0f;
#pragma unroll
    for (int w = 0; w < nw; ++w) S += sw[w] * __expf(sm[w] - M);
    partial[seg * N + row] = make_float2(M, S);
  }
}

__global__ __launch_bounds__(BLK2) void finalize_kernel(
    const float2* __restrict__ partial,  // [SPLIT][N]
    const float* __restrict__ xt,        // [N]
    float* __restrict__ out, int N) {
  const int tid = threadIdx.x;
  float lsum = 0.0f;

  for (int r = tid; r < N; r += BLK2) {
    float2 p[SPLIT];
#pragma unroll
    for (int g = 0; g < SPLIT; ++g) p[g] = partial[g * N + r];
    float M = p[0].x;
#pragma unroll
    for (int g = 1; g < SPLIT; ++g) M = fmaxf(M, p[g].x);
    float S = 0.0f;
#pragma unroll
    for (int g = 0; g < SPLIT; ++g) S += p[g].y * expf(p[g].x - M);

    const float logpt = xt[r] - M - logf(S);
    const float pt = expf(logpt);
    const float om = 1.0f - pt;
    const float w3 = om * om * om;
    // gamma: pt >= 0.5 -> 3; pt < 0.2 -> 5; else -> 3  ==> (pt<0.2) ? 5 : 3
    const float wgt = (pt < 0.2f) ? w3 * om * om : w3;
    lsum += -wgt * logpt;
  }

  // Block reduction over 16 waves.
#pragma unroll
  for (int off = 32; off > 0; off >>= 1) lsum += __shfl_down(lsum, off);
  __shared__ float sw[BLK2 / 64];
  if ((tid & 63) == 0) sw[tid >> 6] = lsum;
  __syncthreads();
  if (tid == 0) {
    float s = 0.0f;
#pragma unroll
    for (int w = 0; w < BLK2 / 64; ++w) s += sw[w];
    out[0] = s;
  }
}

extern "C" void kernel_launch(void* const* d_in, const int* in_sizes, int n_in,
                              void* d_out, int out_size, void* d_ws, size_t ws_size,
                              hipStream_t stream) {
  const float* input = (const float*)d_in[0];
  const int* target = (const int*)d_in[1];
  float* out = (float*)d_out;

  const int N = in_sizes[1];            // 4096 rows
  const int C = in_sizes[0] / N;        // 32000 cols

  float2* partial = (float2*)d_ws;                    // SPLIT*N float2
  float* xt = (float*)((char*)d_ws + (size_t)SPLIT * N * sizeof(float2));

  partial_softmax_kernel<<<dim3(N * SPLIT), dim3(BLOCK), 0, stream>>>(
      input, target, partial, xt, C);
  finalize_kernel<<<dim3(1), dim3(BLK2), 0, stream>>>(partial, xt, out, N);
}